// Round 3
// baseline (36.356 us; speedup 1.0000x reference)
//
#include <hip/hip_runtime.h>

// SIR RK4, B=65536 systems, 200 time points, out (B,200,3) f32 = 157.3 MB.
// Round 3: barrier-free single-wave blocks. A wave64 is lockstep, so the
// LDS transpose needs no s_barrier; removing __syncthreads removes the
// compiler's s_waitcnt vmcnt(0) drain, letting chunk-c stores overlap
// chunk-(c+1) integration.

#define SYS_PER_BLK 64
#define ROW_F   124   // 40 pts * 3 floats = 120, +4 pad (31 float4/row)
#define ROW_F4  31

__global__ __launch_bounds__(64) void sir_rk4_kernel(
    const float* __restrict__ params, float* __restrict__ out)
{
    const int t  = threadIdx.x;
    const int b0 = blockIdx.x * SYS_PER_BLK;
    const int b  = b0 + t;

    __shared__ float lbuf[SYS_PER_BLK * ROW_F];

    const float4 p = reinterpret_cast<const float4*>(params)[b];
    const float beta = p.x, gamma = p.y;
    float S = p.z, I = p.w;
    float R = 1.0f - S - I;

    const float dt = 100.0f / 199.0f;
    const float h2 = 0.5f * dt;
    const float h6 = dt / 6.0f;

    auto step = [&]() {
        float bSI1 = beta * S * I;
        float gI1  = gamma * I;
        float k1S = -bSI1, k1I = bSI1 - gI1, k1R = gI1;
        float S2 = __builtin_fmaf(h2, k1S, S);
        float I2 = __builtin_fmaf(h2, k1I, I);
        float bSI2 = beta * S2 * I2;
        float gI2  = gamma * I2;
        float k2S = -bSI2, k2I = bSI2 - gI2, k2R = gI2;
        float S3 = __builtin_fmaf(h2, k2S, S);
        float I3 = __builtin_fmaf(h2, k2I, I);
        float bSI3 = beta * S3 * I3;
        float gI3  = gamma * I3;
        float k3S = -bSI3, k3I = bSI3 - gI3, k3R = gI3;
        float S4 = __builtin_fmaf(dt, k3S, S);
        float I4 = __builtin_fmaf(dt, k3I, I);
        float bSI4 = beta * S4 * I4;
        float gI4  = gamma * I4;
        float k4S = -bSI4, k4I = bSI4 - gI4, k4R = gI4;
        S = __builtin_fmaf(h6, k1S + 2.0f * (k2S + k3S) + k4S, S);
        I = __builtin_fmaf(h6, k1I + 2.0f * (k2I + k3I) + k4I, I);
        R = __builtin_fmaf(h6, k1R + 2.0f * (k2R + k3R) + k4R, R);
    };

    float4* lrow  = reinterpret_cast<float4*>(&lbuf[t * ROW_F]);
    const float4* lall = reinterpret_cast<const float4*>(lbuf);
    float4* gout  = reinterpret_cast<float4*>(out) + (size_t)b0 * 150;  // 600 f/row

    for (int c = 0; c < 5; ++c) {
        // integrate 40 points (10 groups of 4) into this thread's LDS row
        #pragma unroll
        for (int g = 0; g < 10; ++g) {
            float4 va, vb, vc;
            if (c == 0 && g == 0) { va.x = S; va.y = I; va.z = R; }
            else                  { step(); va.x = S; va.y = I; va.z = R; }
            step(); va.w = S; vb.x = I; vb.y = R;
            step(); vb.z = S; vb.w = I; vc.x = R;
            step(); vc.y = S; vc.z = I; vc.w = R;
            lrow[g * 3 + 0] = va;
            lrow[g * 3 + 1] = vb;
            lrow[g * 3 + 2] = vc;
        }
        // no __syncthreads(): single-wave block, lockstep; compiler's lgkmcnt
        // waits order the LDS transpose, and stores are free to stay in flight
        // across the next integrate phase.
        #pragma unroll 6
        for (int it = 0; it < 30; ++it) {
            int f = it * 64 + t;
            int r = f / 30;
            int q = f - r * 30;
            float4 v = lall[r * ROW_F4 + q];
            gout[(size_t)r * 150 + c * 30 + q] = v;
        }
    }
}

extern "C" void kernel_launch(void* const* d_in, const int* in_sizes, int n_in,
                              void* d_out, int out_size, void* d_ws, size_t ws_size,
                              hipStream_t stream) {
    const float* params = (const float*)d_in[0];
    float* out = (float*)d_out;
    const int B = in_sizes[0] / 4;                 // 65536
    const int grid = B / SYS_PER_BLK;              // 1024 blocks
    sir_rk4_kernel<<<grid, SYS_PER_BLK, 0, stream>>>(params, out);
}